// Round 6
// baseline (354.196 us; speedup 1.0000x reference)
//
#include <hip/hip_runtime.h>
#include <hip/hip_bf16.h>
#include <math.h>

#define N_PTS  100000
#define M_CL   2048
#define E_EDG  65536
#define IN_DIM 512
#define HID    256
// TAU = 0.5 -> 1/TAU = 2.0 ; LAMDA = 1.0 (folded)

typedef unsigned short u16;
typedef __attribute__((ext_vector_type(8))) short bf16x8;
typedef __attribute__((ext_vector_type(4))) float f32x4;

__device__ __forceinline__ u16 f2bf(float f){
  __hip_bfloat16 h = __float2bfloat16(f);
  return *reinterpret_cast<u16*>(&h);
}
__device__ __forceinline__ unsigned pk2(float a, float b){
  return (unsigned)f2bf(a) | ((unsigned)f2bf(b) << 16);
}
__device__ __forceinline__ float bf2f(u16 v){
  return __uint_as_float((unsigned)v << 16);
}
// async global->LDS, 16B per lane. dest must be wave-uniform base + lane*16.
__device__ __forceinline__ void glds16(const u16* g, u16* l){
  __builtin_amdgcn_global_load_lds(
      (const __attribute__((address_space(1))) unsigned int*)(g),
      (__attribute__((address_space(3))) unsigned int*)(l), 16, 0, 0);
}

// ---------------- workspace layout (bytes); ws_size ~819 MB ----------------
static const size_t OFF_POSACC = 0;              // M floats
static const size_t OFF_NEGSUM = 8192;           // M floats
static const size_t OFF_HISTP  = 16384;          // M ints
static const size_t OFF_CURP   = 24576;          // M ints
static const size_t OFF_HISTE  = 32768;          // M ints
static const size_t OFF_CURE   = 40960;          // M ints
static const size_t OFF_LOSS   = 49152;          // 1 double
static const size_t ZERO_BYTES = 49408;
static const size_t OFF_STARTP = 49664;          // M+1 ints
static const size_t OFF_STARTE = 58112;          // M+1 ints
static const size_t OFF_SORTPT = 66560;          // N ints
static const size_t OFF_SCOL   = 466688;         // E ints
static const size_t OFF_SVAL   = 728832;         // E floats
static const size_t OFF_CNT    = 990976;         // M floats
static const size_t OFF_XC     = 999168;         // M*512 f32 = 4 MB (ends 5193472)
static const size_t OFF_Q      = 9387776;        // M*256 f32
static const size_t OFF_HNB    = 11484928;       // M*256 u16 (bf16 hn)
static const size_t OFF_NEGB   = 13582080;       // M*M u16 = 8 MB (ends 21970688)
static const size_t OFF_WT0T   = 22020096;       // 256*512 bf16 = 256 KB
static const size_t OFF_WT1T   = 22282240;       // 256*256 bf16 = 128 KB
static const size_t OFF_XBF    = 33554432;       // N*512 bf16 = 102.4 MB

// ---------------- zero-init (replaces hipMemsetAsync graph node) ----------------
__global__ __launch_bounds__(256) void k_zero(unsigned* __restrict__ p, int n){
  int i = blockIdx.x*256 + threadIdx.x;
  if (i < n) p[i] = 0u;
}

// ---------------- CSR build ----------------
__global__ __launch_bounds__(256) void k_hist(const int* __restrict__ idx, int n, int* __restrict__ hist){
  int i = blockIdx.x*256 + threadIdx.x;
  if (i < n) atomicAdd(&hist[idx[i]], 1);
}

__global__ __launch_bounds__(256) void k_scan(const int* __restrict__ hist, int* __restrict__ start){
  __shared__ int part[256];
  int t = threadIdx.x;
  int v[8]; int s = 0;
#pragma unroll
  for (int j=0;j<8;j++){ v[j] = hist[t*8+j]; s += v[j]; }
  part[t] = s;
  __syncthreads();
  if (t == 0){
    int run = 0;
    for (int i=0;i<256;i++){ int tmp = part[i]; part[i] = run; run += tmp; }
  }
  __syncthreads();
  int run = part[t];
#pragma unroll
  for (int j=0;j<8;j++){ start[t*8+j] = run; run += v[j]; }
  if (t == 255) start[M_CL] = run;
}

__global__ __launch_bounds__(256) void k_scatter_pts(const int* __restrict__ assign, const int* __restrict__ start,
                                                     int* __restrict__ cur, int* __restrict__ out){
  int i = blockIdx.x*256 + threadIdx.x;
  if (i < N_PTS){
    int r = assign[i];
    int p = start[r] + atomicAdd(&cur[r], 1);
    out[p] = i;
  }
}

__global__ __launch_bounds__(256) void k_scatter_edges(const int* __restrict__ rows, const int* __restrict__ cols,
                                                       const float* __restrict__ vals, const int* __restrict__ start,
                                                       int* __restrict__ cur, int* __restrict__ scol,
                                                       float* __restrict__ sval){
  int e = blockIdx.x*256 + threadIdx.x;
  if (e < E_EDG){
    int r = rows[e];
    int p = start[r] + atomicAdd(&cur[r], 1);
    scol[p] = cols[e];
    sval[p] = vals[e];
  }
}

// ---------------- Xc = segsum(p*x), cnt = segsum(p), xbf = bf16(x) ----------------
// 2 half-blocks (wave pairs) process alternate cluster rows; float4 loads.
__global__ __launch_bounds__(256) void k_cluster_agg(const float* __restrict__ x, const float* __restrict__ pv,
                                                     const int* __restrict__ sorted_pt, const int* __restrict__ start,
                                                     float* __restrict__ Xc, float* __restrict__ cnt,
                                                     u16* __restrict__ xbf){
  const int m = blockIdx.x;
  const int t = threadIdx.x;
  const int half = t >> 7;       // 0/1: waves {0,1} vs {2,3}
  const int u = t & 127;         // dim unit: dims [u*4, u*4+4)
  const int s0 = start[m], s1 = start[m+1];
  f32x4 a = {0.f,0.f,0.f,0.f};
  float c = 0.f;
  for (int p = s0 + half; p < s1; p += 2){
    int row = sorted_pt[p];
    float w = pv[row];
    f32x4 xv = *reinterpret_cast<const f32x4*>(x + (size_t)row*IN_DIM + u*4);
    a.x = fmaf(w, xv.x, a.x); a.y = fmaf(w, xv.y, a.y);
    a.z = fmaf(w, xv.z, a.z); a.w = fmaf(w, xv.w, a.w);
    c += w;
    uint2 pk; pk.x = pk2(xv.x, xv.y); pk.y = pk2(xv.z, xv.w);
    *reinterpret_cast<uint2*>(xbf + (size_t)row*IN_DIM + u*4) = pk;
  }
  __shared__ __align__(16) float sh[128*4];
  __shared__ float shc[2];
  if (half == 1) *reinterpret_cast<f32x4*>(sh + u*4) = a;
  if (t == 0)   shc[0] = c;     // c uniform within a half
  if (t == 128) shc[1] = c;
  __syncthreads();
  if (half == 0){
    f32x4 b = *reinterpret_cast<const f32x4*>(sh + u*4);
    a.x += b.x; a.y += b.y; a.z += b.z; a.w += b.w;
    *reinterpret_cast<f32x4*>(Xc + (size_t)m*IN_DIM + u*4) = a;
    if (t == 0) cnt[m] = shc[0] + shc[1];
  }
}

// ---------------- weight transpose+convert: W[k][n] f32 -> Wt[n][k] bf16 ----------------
template<int K>
__global__ __launch_bounds__(256) void k_transpose_bf16(const float* __restrict__ W, u16* __restrict__ Wt){
  int o = blockIdx.x*256 + threadIdx.x;   // o = n*K + k
  int n = o / K, k = o % K;
  Wt[o] = f2bf(W[(size_t)k*HID + n]);
}

// ---------------- fused M-scale chain: encoder(2)+projector(2)+both norms ----------------
template<int K>
__device__ __forceinline__ void mc_layer(const float* __restrict__ W, const float* act, int t, float acc[4]){
#pragma unroll
  for (int r=0;r<4;r++) acc[r] = 0.f;
#pragma unroll 2
  for (int k=0;k<K;k+=4){
    float w0 = W[(size_t)(k+0)*HID + t];
    float w1 = W[(size_t)(k+1)*HID + t];
    float w2 = W[(size_t)(k+2)*HID + t];
    float w3 = W[(size_t)(k+3)*HID + t];
#pragma unroll
    for (int r=0;r<4;r++){
      float4 av = *reinterpret_cast<const float4*>(act + r*K + k);
      acc[r] = fmaf(av.x, w0, acc[r]);
      acc[r] = fmaf(av.y, w1, acc[r]);
      acc[r] = fmaf(av.z, w2, acc[r]);
      acc[r] = fmaf(av.w, w3, acc[r]);
    }
  }
}

__global__ __launch_bounds__(256) void k_mchain(
    const float* __restrict__ Xc, const float* __restrict__ cnt,
    const float* __restrict__ We0, const float* __restrict__ be0,
    const float* __restrict__ We1, const float* __restrict__ be1,
    const float* __restrict__ Wp0, const float* __restrict__ bp0,
    const float* __restrict__ Wp1, const float* __restrict__ bp1,
    u16* __restrict__ hnb, float* __restrict__ q){
  __shared__ __align__(16) float a_sh[4*512];
  __shared__ __align__(16) float b_sh[4*256];
  __shared__ float part[4][4];
  const int t = threadIdx.x;
  const int rb = blockIdx.x*4;
  for (int i=t; i<4*128; i+=256){
    int r = i>>7, k4 = i&127;
    reinterpret_cast<float4*>(a_sh + r*512)[k4] =
      reinterpret_cast<const float4*>(Xc + (size_t)(rb+r)*IN_DIM)[k4];
  }
  float cv[4];
#pragma unroll
  for (int r=0;r<4;r++) cv[r] = cnt[rb+r];
  __syncthreads();

  float acc[4], v[4];
  mc_layer<512>(We0, a_sh, t, acc);
  {
    float b = be0[t];
#pragma unroll
    for (int r=0;r<4;r++) b_sh[r*256+t] = fmaf(cv[r], b, acc[r]);
  }
  __syncthreads();
  mc_layer<256>(We1, b_sh, t, acc);
  {
    float b = be1[t];
#pragma unroll
    for (int r=0;r<4;r++){
      v[r] = fmaf(cv[r], b, acc[r]);
      float s = v[r]*v[r];
#pragma unroll
      for (int off=32;off;off>>=1) s += __shfl_xor(s, off, 64);
      if ((t&63) == 0) part[t>>6][r] = s;
      a_sh[r*256+t] = v[r];
    }
  }
  __syncthreads();
#pragma unroll
  for (int r=0;r<4;r++){
    float tot = part[0][r]+part[1][r]+part[2][r]+part[3][r];
    float inv = 1.0f / fmaxf(sqrtf(tot), 1e-12f);
    hnb[(size_t)(rb+r)*HID + t] = f2bf(v[r]*inv);
  }
  mc_layer<256>(Wp0, a_sh, t, acc);
  {
    float b = bp0[t];
#pragma unroll
    for (int r=0;r<4;r++) b_sh[r*256+t] = fmaxf(acc[r]+b, 0.f);
  }
  __syncthreads();
  mc_layer<256>(Wp1, b_sh, t, acc);
  {
    float b = bp1[t];
#pragma unroll
    for (int r=0;r<4;r++){
      v[r] = acc[r] + b;
      float s = v[r]*v[r];
#pragma unroll
      for (int off=32;off;off>>=1) s += __shfl_xor(s, off, 64);
      if ((t&63) == 0) part[t>>6][r] = s;
    }
  }
  __syncthreads();
#pragma unroll
  for (int r=0;r<4;r++){
    float tot = part[0][r]+part[1][r]+part[2][r]+part[3][r];
    float inv = 1.0f / fmaxf(sqrtf(tot), 1e-12f);
    q[(size_t)(rb+r)*HID + t] = v[r]*inv;
  }
}

// ---------------- fused target encoder (block GEMM, all-glds staging) ----------------
__global__ __launch_bounds__(256,2) void k_target_mfma(
    const u16* __restrict__ xbf, const u16* __restrict__ Wt0t, const float* __restrict__ bt0,
    const u16* __restrict__ Wt1t, const float* __restrict__ bt1,
    const float* __restrict__ q, const int* __restrict__ assign,
    const float* __restrict__ pv, float* __restrict__ posacc){
  __shared__ u16 ws[2*8192];        // 2 x [256 n][32 k] bf16 = 32 KB
  __shared__ u16 act[16384];        // [64 m][256 n] bf16 = 32 KB; first 8 KB doubles as xs dbuf
  __shared__ float red[2][4][4][16];
  u16* xs = act;

  const int t  = threadIdx.x;
  const int w  = t >> 6;
  const int l  = t & 63;
  const int c  = l & 15;
  const int lg = l >> 4;
  const int gm0 = blockIdx.x * 64;

  const int sxr = w*16 + (l>>2);
  int sxg = gm0 + sxr; if (sxg >= N_PTS) sxg = N_PTS-1;
  const u16* xsrc = xbf + (size_t)sxg*IN_DIM + ((l&3) ^ ((sxr>>1)&3))*8;
  u16* xdst = xs + (w*64 + l)*8;

  f32x4 acc[4][4];
#pragma unroll
  for (int i=0;i<4;i++)
#pragma unroll
    for (int j=0;j<4;j++){ acc[i][j].x=0.f; acc[i][j].y=0.f; acc[i][j].z=0.f; acc[i][j].w=0.f; }

  #define STAGE_W(Wt, K, k0, buf) do { \
    _Pragma("unroll") \
    for (int i_=0;i_<4;i_++){ \
      int row_ = w*64 + i_*16 + (l>>2); \
      int ug_  = (l&3) ^ ((row_>>1)&3); \
      glds16((Wt) + (size_t)row_*(K) + (k0) + ug_*8, \
             ws + (buf)*8192 + (w*64 + i_*16)*32 + l*8); \
    } } while(0)
  #define STAGE_X(k0, buf) glds16(xsrc + (k0), xdst + (buf)*2048)

  const int su = lg ^ ((c>>1)&3);

  // ================= phase 1: t = x @ Wt0  (K=512, 16 slabs) =================
  STAGE_W(Wt0t, IN_DIM, 0, 0);
  STAGE_X(0, 0);
  __syncthreads();
#pragma unroll
  for (int ks=0; ks<16; ks++){
    int buf = ks & 1;
    if (ks < 15){ STAGE_W(Wt0t, IN_DIM, (ks+1)*32, buf^1); STAGE_X((ks+1)*32, buf^1); }
    bf16x8 bfr[4];
#pragma unroll
    for (int mf=0; mf<4; mf++)
      bfr[mf] = *reinterpret_cast<const bf16x8*>(xs + buf*2048 + ((mf*16+c)*4 + su)*8);
#pragma unroll
    for (int nf=0; nf<4; nf++){
      bf16x8 afr = *reinterpret_cast<const bf16x8*>(ws + buf*8192 + ((w*64+nf*16+c)*4 + su)*8);
#pragma unroll
      for (int mf=0; mf<4; mf++)
        acc[mf][nf] = __builtin_amdgcn_mfma_f32_16x16x32_bf16(afr, bfr[mf], acc[mf][nf], 0,0,0);
    }
    __syncthreads();
  }

  // ---- epilogue-1: acc + bt0 -> act (bf16, unit-swizzled) ----
#pragma unroll
  for (int nf=0; nf<4; nf++){
    f32x4 bias = *reinterpret_cast<const f32x4*>(bt0 + w*64 + nf*16 + lg*4);
#pragma unroll
    for (int mf=0; mf<4; mf++){
      int m = mf*16 + c;
      f32x4 v = acc[mf][nf] + bias;
      uint2 p; p.x = pk2(v.x, v.y); p.y = pk2(v.z, v.w);
      int u = (w*8 + nf*2 + (lg>>1)) ^ (c&7);
      *reinterpret_cast<uint2*>(act + (m*32 + u)*8 + (lg&1)*4) = p;
    }
  }
#pragma unroll
  for (int i=0;i<4;i++)
#pragma unroll
    for (int j=0;j<4;j++){ acc[i][j].x=0.f; acc[i][j].y=0.f; acc[i][j].z=0.f; acc[i][j].w=0.f; }
  STAGE_W(Wt1t, HID, 0, 0);
  __syncthreads();

  // ================= phase 2: v = t @ Wt1  (K=256, 8 slabs) =================
#pragma unroll
  for (int ks=0; ks<8; ks++){
    int buf = ks & 1;
    if (ks < 7) STAGE_W(Wt1t, HID, (ks+1)*32, buf^1);
    bf16x8 bfr[4];
#pragma unroll
    for (int mf=0; mf<4; mf++){
      int m = mf*16 + c;
      int u = (ks*4 + lg) ^ (c&7);
      bfr[mf] = *reinterpret_cast<const bf16x8*>(act + (m*32 + u)*8);
    }
#pragma unroll
    for (int nf=0; nf<4; nf++){
      bf16x8 afr = *reinterpret_cast<const bf16x8*>(ws + buf*8192 + ((w*64+nf*16+c)*4 + su)*8);
#pragma unroll
      for (int mf=0; mf<4; mf++)
        acc[mf][nf] = __builtin_amdgcn_mfma_f32_16x16x32_bf16(afr, bfr[mf], acc[mf][nf], 0,0,0);
    }
    __syncthreads();
  }

  // ---- epilogue-2: +bt1, partial ||v|| and v.q, cross-wave combine ----
#pragma unroll
  for (int mf=0; mf<4; mf++){
    int gm = gm0 + mf*16 + c;
    int cl = assign[(gm < N_PTS) ? gm : (N_PTS-1)];
    const float* qrow = q + (size_t)cl*HID + w*64 + lg*4;
    float ss = 0.f, d = 0.f;
#pragma unroll
    for (int nf=0; nf<4; nf++){
      f32x4 b  = *reinterpret_cast<const f32x4*>(bt1 + w*64 + nf*16 + lg*4);
      f32x4 qv = *reinterpret_cast<const f32x4*>(qrow + nf*16);
      f32x4 v  = acc[mf][nf] + b;
      ss = fmaf(v.x,v.x, fmaf(v.y,v.y, fmaf(v.z,v.z, fmaf(v.w,v.w, ss))));
      d  = fmaf(v.x,qv.x, fmaf(v.y,qv.y, fmaf(v.z,qv.z, fmaf(v.w,qv.w, d))));
    }
    ss += __shfl_xor(ss, 16, 64); ss += __shfl_xor(ss, 32, 64);
    d  += __shfl_xor(d , 16, 64); d  += __shfl_xor(d , 32, 64);
    if (lg == 0){ red[0][w][mf][c] = ss; red[1][w][mf][c] = d; }
  }
  __syncthreads();
  if (t < 64){
    int gm = gm0 + t;
    if (gm < N_PTS){
      int mf = t>>4, cc = t&15;
      float ss = red[0][0][mf][cc]+red[0][1][mf][cc]+red[0][2][mf][cc]+red[0][3][mf][cc];
      float d  = red[1][0][mf][cc]+red[1][1][mf][cc]+red[1][2][mf][cc]+red[1][3][mf][cc];
      float inv = 1.0f / fmaxf(sqrtf(ss), 1e-12f);
      atomicAdd(&posacc[assign[gm]], pv[gm] * d * inv * 2.0f);   // * (1/TAU)
    }
  }
  #undef STAGE_W
  #undef STAGE_X
}

// ---------------- neg = exp(hn@hn^T / TAU) as bf16 + f32 rowsum (MFMA) ----------------
__global__ __launch_bounds__(256,2) void k_neg_mfma(
    const u16* __restrict__ hnb, u16* __restrict__ negb, float* __restrict__ negsum){
  __shared__ u16 wsb[2*8192];
  __shared__ u16 xsb[2*2048];
  const int t  = threadIdx.x;
  const int w  = t >> 6;
  const int l  = t & 63;
  const int c  = l & 15;
  const int lg = l >> 4;
  const int j0 = blockIdx.x * 256;
  const int i0 = blockIdx.y * 64;

  const int sxr = w*16 + (l>>2);
  const u16* xsrc = hnb + (size_t)(i0+sxr)*HID + ((l&3) ^ ((sxr>>1)&3))*8;
  u16* xdst = xsb + (w*64 + l)*8;

  f32x4 acc[4][4];
#pragma unroll
  for (int i=0;i<4;i++)
#pragma unroll
    for (int j=0;j<4;j++){ acc[i][j].x=0.f; acc[i][j].y=0.f; acc[i][j].z=0.f; acc[i][j].w=0.f; }

  #define NSTAGE_W(k0, buf) do { \
    _Pragma("unroll") \
    for (int i_=0;i_<4;i_++){ \
      int row_ = w*64 + i_*16 + (l>>2); \
      int ug_  = (l&3) ^ ((row_>>1)&3); \
      glds16(hnb + (size_t)(j0+row_)*HID + (k0) + ug_*8, \
             wsb + (buf)*8192 + (w*64 + i_*16)*32 + l*8); \
    } } while(0)
  #define NSTAGE_X(k0, buf) glds16(xsrc + (k0), xdst + (buf)*2048)

  NSTAGE_W(0, 0);
  NSTAGE_X(0, 0);
  __syncthreads();
  const int su = lg ^ ((c>>1)&3);
#pragma unroll
  for (int ks=0; ks<8; ks++){
    int buf = ks & 1;
    if (ks < 7){ NSTAGE_W((ks+1)*32, buf^1); NSTAGE_X((ks+1)*32, buf^1); }
    bf16x8 bfr[4];
#pragma unroll
    for (int mf=0; mf<4; mf++)
      bfr[mf] = *reinterpret_cast<const bf16x8*>(xsb + buf*2048 + ((mf*16+c)*4 + su)*8);
#pragma unroll
    for (int nf=0; nf<4; nf++){
      bf16x8 afr = *reinterpret_cast<const bf16x8*>(wsb + buf*8192 + ((w*64+nf*16+c)*4 + su)*8);
#pragma unroll
      for (int mf=0; mf<4; mf++)
        acc[mf][nf] = __builtin_amdgcn_mfma_f32_16x16x32_bf16(afr, bfr[mf], acc[mf][nf], 0,0,0);
    }
    __syncthreads();
  }

#pragma unroll
  for (int mf=0; mf<4; mf++){
    int i = i0 + mf*16 + c;
    float rs = 0.f;
#pragma unroll
    for (int nf=0; nf<4; nf++){
      f32x4 a = acc[mf][nf];
      float e0 = __expf(a.x*2.0f), e1 = __expf(a.y*2.0f);
      float e2 = __expf(a.z*2.0f), e3 = __expf(a.w*2.0f);
      rs += e0+e1+e2+e3;
      uint2 p; p.x = pk2(e0, e1); p.y = pk2(e2, e3);
      *reinterpret_cast<uint2*>(negb + (size_t)i*M_CL + j0 + w*64 + nf*16 + lg*4) = p;
    }
    rs += __shfl_xor(rs, 16, 64); rs += __shfl_xor(rs, 32, 64);
    if (lg == 0) atomicAdd(&negsum[i], rs);
  }
  #undef NSTAGE_W
  #undef NSTAGE_X
}

// ---------------- loss: thread t handles cols [t*8, t*8+8) -> 16B row gathers ----------------
__global__ __launch_bounds__(256) void k_loss(const u16* __restrict__ negb, const float* __restrict__ negsum,
                                              const float* __restrict__ posacc, const int* __restrict__ start,
                                              const int* __restrict__ scol, const float* __restrict__ sval,
                                              double* __restrict__ loss){
  const int i = blockIdx.x, t = threadIdx.x;
  float ps[8] = {};
  const int s0 = start[i], s1 = start[i+1];
  for (int e=s0;e<s1;e++){
    int c = scol[e];
    float v = sval[e];
    bf16x8 r = *reinterpret_cast<const bf16x8*>(negb + (size_t)c*M_CL + t*8);
#pragma unroll
    for (int jj=0;jj<8;jj++) ps[jj] = fmaf(v, bf2f((u16)r[jj]), ps[jj]);
  }
  float pos = __expf(posacc[i]);
  f32x4 nsa = *reinterpret_cast<const f32x4*>(negsum + t*8);
  f32x4 nsb = *reinterpret_cast<const f32x4*>(negsum + t*8 + 4);
  float ns[8] = {nsa.x,nsa.y,nsa.z,nsa.w,nsb.x,nsb.y,nsb.z,nsb.w};
  float part = 0.f;
#pragma unroll
  for (int jj=0;jj<8;jj++)
    part += __logf(pos + ns[jj]) - __logf(pos + ps[jj]);  // LAMDA = 1
#pragma unroll
  for (int off=32;off;off>>=1) part += __shfl_xor(part, off, 64);
  __shared__ float wsum[4];
  if ((t&63) == 0) wsum[t>>6] = part;
  __syncthreads();
  if (t == 0){
    double s = (double)wsum[0] + (double)wsum[1] + (double)wsum[2] + (double)wsum[3];
    atomicAdd(loss, s);
  }
}

__global__ void k_finalize(const double* __restrict__ loss, float* __restrict__ out){
  if (threadIdx.x == 0 && blockIdx.x == 0)
    out[0] = (float)(loss[0] / ((double)M_CL * (double)M_CL));
}

// ---------------- launch ----------------
extern "C" void kernel_launch(void* const* d_in, const int* in_sizes, int n_in,
                              void* d_out, int out_size, void* d_ws, size_t ws_size,
                              hipStream_t stream){
  const float* x    = (const float*)d_in[0];
  const float* We0  = (const float*)d_in[1];
  const float* be0  = (const float*)d_in[2];
  const float* We1  = (const float*)d_in[3];
  const float* be1  = (const float*)d_in[4];
  const float* Wt0  = (const float*)d_in[5];
  const float* bt0  = (const float*)d_in[6];
  const float* Wt1  = (const float*)d_in[7];
  const float* bt1  = (const float*)d_in[8];
  const float* Wp0  = (const float*)d_in[9];
  const float* bp0  = (const float*)d_in[10];
  const float* Wp1  = (const float*)d_in[11];
  const float* bp1  = (const float*)d_in[12];
  const float* pv   = (const float*)d_in[13];
  const float* cgv  = (const float*)d_in[14];
  const int*   pas  = (const int*)d_in[15];
  const int*   cgr  = (const int*)d_in[16];
  const int*   cgc  = (const int*)d_in[17];

  char* ws = (char*)d_ws;
  float*  posacc  = (float*)(ws + OFF_POSACC);
  float*  negsum  = (float*)(ws + OFF_NEGSUM);
  int*    hist_p  = (int*)  (ws + OFF_HISTP);
  int*    cur_p   = (int*)  (ws + OFF_CURP);
  int*    hist_e  = (int*)  (ws + OFF_HISTE);
  int*    cur_e   = (int*)  (ws + OFF_CURE);
  double* lossd   = (double*)(ws + OFF_LOSS);
  int*    start_p = (int*)  (ws + OFF_STARTP);
  int*    start_e = (int*)  (ws + OFF_STARTE);
  int*    sortpt  = (int*)  (ws + OFF_SORTPT);
  int*    scol    = (int*)  (ws + OFF_SCOL);
  float*  sval    = (float*)(ws + OFF_SVAL);
  float*  cnt     = (float*)(ws + OFF_CNT);
  float*  Xc      = (float*)(ws + OFF_XC);
  float*  qb      = (float*)(ws + OFF_Q);
  u16*    hnb     = (u16*)  (ws + OFF_HNB);
  u16*    negb    = (u16*)  (ws + OFF_NEGB);
  u16*    Wt0t    = (u16*)  (ws + OFF_WT0T);
  u16*    Wt1t    = (u16*)  (ws + OFF_WT1T);
  u16*    xbf     = (u16*)  (ws + OFF_XBF);

  k_zero<<<(ZERO_BYTES/4 + 255)/256, 256, 0, stream>>>((unsigned*)ws, ZERO_BYTES/4);

  k_hist<<<(N_PTS+255)/256, 256, 0, stream>>>(pas, N_PTS, hist_p);
  k_hist<<<(E_EDG+255)/256, 256, 0, stream>>>(cgr, E_EDG, hist_e);
  k_scan<<<1, 256, 0, stream>>>(hist_p, start_p);
  k_scan<<<1, 256, 0, stream>>>(hist_e, start_e);
  k_scatter_pts<<<(N_PTS+255)/256, 256, 0, stream>>>(pas, start_p, cur_p, sortpt);
  k_scatter_edges<<<(E_EDG+255)/256, 256, 0, stream>>>(cgr, cgc, cgv, start_e, cur_e, scol, sval);

  k_transpose_bf16<IN_DIM><<<IN_DIM, 256, 0, stream>>>(Wt0, Wt0t);
  k_transpose_bf16<HID  ><<<HID,    256, 0, stream>>>(Wt1, Wt1t);

  k_cluster_agg<<<M_CL, 256, 0, stream>>>(x, pv, sortpt, start_p, Xc, cnt, xbf);

  k_mchain<<<M_CL/4, 256, 0, stream>>>(Xc, cnt, We0, be0, We1, be1, Wp0, bp0, Wp1, bp1, hnb, qb);

  k_target_mfma<<<(N_PTS+63)/64, 256, 0, stream>>>(xbf, Wt0t, bt0, Wt1t, bt1, qb, pas, pv, posacc);

  dim3 gneg(M_CL/256, M_CL/64);
  k_neg_mfma<<<gneg, 256, 0, stream>>>(hnb, negb, negsum);

  k_loss<<<M_CL, 256, 0, stream>>>(negb, negsum, posacc, start_e, scol, sval, lossd);
  k_finalize<<<1, 64, 0, stream>>>(lossd, (float*)d_out);
}